// Round 2
// baseline (2844.310 us; speedup 1.0000x reference)
//
#include <hip/hip_runtime.h>

// ---------------------------------------------------------------------------
// SGConv (K=2): out = A^2 (X W^T) + b
//   A = D^{-1/2} (Adj_clamped + I) D^{-1/2}
// N=50000, E=800000, T=256, H=128.
// edge_index arrives as int32 (harness converts all integer inputs to int32).
// Buffer cycle:  d_out <- XW^T ;  ws.h1 <- A*d_out ;  d_out <- A*ws.h1 + b
// ---------------------------------------------------------------------------

// y[r][h] = dot(x[r][:], W[h][:])   (T=256, H=128)
__global__ __launch_bounds__(128) void k_transform(
    const float* __restrict__ x, const float* __restrict__ W,
    float* __restrict__ y, int N)
{
    constexpr int T = 256, H = 128, R = 16;
    __shared__ float xs[R][T];
    const int h  = threadIdx.x;          // 0..127 -> output feature
    const int r0 = blockIdx.x * R;

    // stage R rows of x into LDS (float4, coalesced)
    for (int i = threadIdx.x; i < R * (T / 4); i += 128) {
        const int rr  = i / (T / 4);
        const int t4  = i % (T / 4);
        const int row = r0 + rr;
        float4 v = make_float4(0.f, 0.f, 0.f, 0.f);
        if (row < N)
            v = reinterpret_cast<const float4*>(x)[(size_t)row * (T / 4) + t4];
        reinterpret_cast<float4*>(&xs[rr][0])[t4] = v;
    }
    __syncthreads();

    float acc[R];
#pragma unroll
    for (int k = 0; k < R; ++k) acc[k] = 0.f;

    const float4* W4 = reinterpret_cast<const float4*>(W) + (size_t)h * (T / 4);
    for (int t4 = 0; t4 < T / 4; ++t4) {
        const float4 wv = W4[t4];
#pragma unroll
        for (int k = 0; k < R; ++k) {
            const float4 xv = reinterpret_cast<const float4*>(&xs[k][0])[t4];
            acc[k] += wv.x * xv.x + wv.y * xv.y + wv.z * xv.z + wv.w * xv.w;
        }
    }

#pragma unroll
    for (int k = 0; k < R; ++k) {
        const int row = r0 + k;
        if (row < N) y[(size_t)row * H + h] = acc[k];
    }
}

__global__ __launch_bounds__(256) void k_deg_init(float* __restrict__ deg, int N)
{
    int i = blockIdx.x * blockDim.x + threadIdx.x;
    if (i < N) deg[i] = 1.0f;  // self-loop weight
}

__global__ __launch_bounds__(256) void k_deg_scatter(
    const int* __restrict__ cols, const float* __restrict__ ew,
    float* __restrict__ deg, int E)
{
    int e = blockIdx.x * blockDim.x + threadIdx.x;
    if (e >= E) return;
    float w = ew[e];
    w = (w > 0.0f) ? w : 1e-7f;          // elu(w)<=0  <=>  w<=0
    atomicAdd(&deg[cols[e]], w);
}

__global__ __launch_bounds__(256) void k_dis(
    const float* __restrict__ deg, float* __restrict__ dis, int N)
{
    int i = blockIdx.x * blockDim.x + threadIdx.x;
    if (i < N) {
        float d = deg[i];
        dis[i] = (d > 0.0f) ? rsqrtf(d) : 0.0f;
    }
}

__global__ __launch_bounds__(256) void k_norm(
    const int* __restrict__ rows, const int* __restrict__ cols,
    const float* __restrict__ ew, const float* __restrict__ dis,
    float* __restrict__ norm, int E)
{
    int e = blockIdx.x * blockDim.x + threadIdx.x;
    if (e >= E) return;
    float w = ew[e];
    w = (w > 0.0f) ? w : 1e-7f;
    norm[e] = dis[rows[e]] * w * dis[cols[e]];
}

// h_out[i][:] = dis[i]^2 * h_in[i][:]  (+ b if provided)   -- self-loop term
__global__ __launch_bounds__(256) void k_hop_init(
    const float* __restrict__ dis, const float* __restrict__ hin,
    const float* __restrict__ bias,  // may be nullptr
    float* __restrict__ hout, int N)
{
    constexpr int H4 = 32;  // H/4
    int idx = blockIdx.x * blockDim.x + threadIdx.x;  // over N*H4
    if (idx >= N * H4) return;
    int i = idx >> 5;
    int q = idx & 31;
    float d  = dis[i];
    float d2 = d * d;
    float4 v = reinterpret_cast<const float4*>(hin)[(size_t)i * H4 + q];
    float4 o;
    o.x = d2 * v.x; o.y = d2 * v.y; o.z = d2 * v.z; o.w = d2 * v.w;
    if (bias) {
        float4 bv = reinterpret_cast<const float4*>(bias)[q];
        o.x += bv.x; o.y += bv.y; o.z += bv.z; o.w += bv.w;
    }
    reinterpret_cast<float4*>(hout)[(size_t)i * H4 + q] = o;
}

// h_out[col][:] += norm[e] * h_in[row][:]   (32 lanes per edge, float4 each)
__global__ __launch_bounds__(256) void k_hop_scatter(
    const int* __restrict__ rows, const int* __restrict__ cols,
    const float* __restrict__ norm,
    const float* __restrict__ hin, float* __restrict__ hout,
    long long total)
{
    constexpr int H4 = 32;  // H/4
    long long idx = (long long)blockIdx.x * blockDim.x + threadIdx.x;
    if (idx >= total) return;
    int e = (int)(idx >> 5);
    int q = (int)(idx & 31);
    int r = rows[e];
    int c = cols[e];
    float nm = norm[e];
    float4 v = reinterpret_cast<const float4*>(hin)[(size_t)r * H4 + q];
    float* dst = &hout[((size_t)c * H4 + q) * 4];
    atomicAdd(dst + 0, nm * v.x);
    atomicAdd(dst + 1, nm * v.y);
    atomicAdd(dst + 2, nm * v.z);
    atomicAdd(dst + 3, nm * v.w);
}

extern "C" void kernel_launch(void* const* d_in, const int* in_sizes, int n_in,
                              void* d_out, int out_size, void* d_ws, size_t ws_size,
                              hipStream_t stream)
{
    const float* x  = (const float*)d_in[0];
    const int*   ei = (const int*)d_in[1];     // int32! (harness converts)
    const float* ew = (const float*)d_in[2];
    const float* W  = (const float*)d_in[3];
    const float* b  = (const float*)d_in[4];

    const int E  = in_sizes[2];
    const int H  = in_sizes[4];        // 128
    const int T  = in_sizes[3] / H;    // 256
    const int N  = in_sizes[0] / T;    // 50000

    const int* rows = ei;              // edge_index[0] = source
    const int* cols = ei + E;          // edge_index[1] = target (aggregation)

    float* wsf  = (float*)d_ws;
    float* h1   = wsf;                      // N*H   (25.6 MB)
    float* deg  = h1  + (size_t)N * H;      // N
    float* dis  = deg + N;                  // N
    float* norm = dis + N;                  // E
    // total ws: N*H*4 + 2*N*4 + E*4 ≈ 29 MB

    float* out = (float*)d_out;

    // 1. out <- X W^T   (use d_out as the y buffer; fully overwritten)
    {
        constexpr int R = 16;
        int grid = (N + R - 1) / R;
        k_transform<<<grid, 128, 0, stream>>>(x, W, out, N);
    }
    // 2. deg / dis
    k_deg_init<<<(N + 255) / 256, 256, 0, stream>>>(deg, N);
    k_deg_scatter<<<(E + 255) / 256, 256, 0, stream>>>(cols, ew, deg, E);
    k_dis<<<(N + 255) / 256, 256, 0, stream>>>(deg, dis, N);
    // 3. per-edge norm (reused by both hops)
    k_norm<<<(E + 255) / 256, 256, 0, stream>>>(rows, cols, ew, dis, norm, E);

    const long long total = (long long)E * (H / 4);
    const int gs = (int)((total + 255) / 256);
    const int gi = (N * (H / 4) + 255) / 256;

    // 4. hop 1: h1 = A out
    k_hop_init<<<gi, 256, 0, stream>>>(dis, out, nullptr, h1, N);
    k_hop_scatter<<<gs, 256, 0, stream>>>(rows, cols, norm, out, h1, total);

    // 5. hop 2: out = A h1 + b
    k_hop_init<<<gi, 256, 0, stream>>>(dis, h1, b, out, N);
    k_hop_scatter<<<gs, 256, 0, stream>>>(rows, cols, norm, h1, out, total);
}

// Round 3
// 340.126 us; speedup vs baseline: 8.3625x; 8.3625x over previous
//
#include <hip/hip_runtime.h>

// ---------------------------------------------------------------------------
// SGConv (K=2): out = A^2 (X W^T) + b,  A = D^{-1/2}(Adj_clamped + I)D^{-1/2}
// N=50000, E=800000, T=256, H=128 (H=128 structural: 64 lanes x float2).
// edge_index arrives as int32 (harness converts integer inputs).
//
// Strategy: build CSR by destination once (histogram -> scan -> permute),
// then each hop is an atomic-free gather: one wave per dst node.
// Buffer cycle: d_out <- XW^T ; ws.h1 <- A*d_out ; d_out <- A*ws.h1 + b
// ---------------------------------------------------------------------------

// y[r][h] = dot(x[r][:], W[h][:])   (T=256, H=128)
__global__ __launch_bounds__(128) void k_transform(
    const float* __restrict__ x, const float* __restrict__ W,
    float* __restrict__ y, int N)
{
    constexpr int T = 256, H = 128, R = 16;
    __shared__ float xs[R][T];
    const int h  = threadIdx.x;
    const int r0 = blockIdx.x * R;

    for (int i = threadIdx.x; i < R * (T / 4); i += 128) {
        const int rr  = i / (T / 4);
        const int t4  = i % (T / 4);
        const int row = r0 + rr;
        float4 v = make_float4(0.f, 0.f, 0.f, 0.f);
        if (row < N)
            v = reinterpret_cast<const float4*>(x)[(size_t)row * (T / 4) + t4];
        reinterpret_cast<float4*>(&xs[rr][0])[t4] = v;
    }
    __syncthreads();

    float acc[R];
#pragma unroll
    for (int k = 0; k < R; ++k) acc[k] = 0.f;

    const float4* W4 = reinterpret_cast<const float4*>(W) + (size_t)h * (T / 4);
    for (int t4 = 0; t4 < T / 4; ++t4) {
        const float4 wv = W4[t4];
#pragma unroll
        for (int k = 0; k < R; ++k) {
            const float4 xv = reinterpret_cast<const float4*>(&xs[k][0])[t4];
            acc[k] += wv.x * xv.x + wv.y * xv.y + wv.z * xv.z + wv.w * xv.w;
        }
    }

#pragma unroll
    for (int k = 0; k < R; ++k) {
        const int row = r0 + k;
        if (row < N) y[(size_t)row * H + h] = acc[k];
    }
}

// deg[i]=1 (self-loop), counts[i]=0
__global__ __launch_bounds__(256) void k_init(
    float* __restrict__ deg, int* __restrict__ counts, int N)
{
    int i = blockIdx.x * blockDim.x + threadIdx.x;
    if (i < N) { deg[i] = 1.0f; counts[i] = 0; }
}

// deg[col] += clamp(w); counts[col] += 1
__global__ __launch_bounds__(256) void k_deg_count(
    const int* __restrict__ cols, const float* __restrict__ ew,
    float* __restrict__ deg, int* __restrict__ counts, int E)
{
    int e = blockIdx.x * blockDim.x + threadIdx.x;
    if (e >= E) return;
    float w = ew[e];
    w = (w > 0.0f) ? w : 1e-7f;          // elu(w)<=0  <=>  w<=0
    int c = cols[e];
    atomicAdd(&deg[c], w);
    atomicAdd(&counts[c], 1);
}

// deg -> dis = rsqrt(deg)  in place (deg >= 1 always)
__global__ __launch_bounds__(256) void k_dis(float* __restrict__ deg, int N)
{
    int i = blockIdx.x * blockDim.x + threadIdx.x;
    if (i < N) deg[i] = rsqrtf(deg[i]);
}

// per-block exclusive scan of counts -> colp, block totals -> bsum
__global__ __launch_bounds__(256) void k_scan_partial(
    const int* __restrict__ counts, int* __restrict__ colp,
    int* __restrict__ bsum, int N)
{
    __shared__ int sh[256];
    int i = blockIdx.x * 256 + threadIdx.x;
    int v = (i < N) ? counts[i] : 0;
    sh[threadIdx.x] = v;
    __syncthreads();
    for (int off = 1; off < 256; off <<= 1) {
        int t = (threadIdx.x >= off) ? sh[threadIdx.x - off] : 0;
        __syncthreads();
        sh[threadIdx.x] += t;
        __syncthreads();
    }
    if (i < N) colp[i] = sh[threadIdx.x] - v;   // exclusive
    if (threadIdx.x == 255) bsum[blockIdx.x] = sh[255];
}

// exclusive scan of bsum in place (nb <= 1024)
__global__ __launch_bounds__(1024) void k_scan_bsum(int* __restrict__ bsum, int nb)
{
    __shared__ int sh[1024];
    int v = ((int)threadIdx.x < nb) ? bsum[threadIdx.x] : 0;
    sh[threadIdx.x] = v;
    __syncthreads();
    for (int off = 1; off < 1024; off <<= 1) {
        int t = ((int)threadIdx.x >= off) ? sh[threadIdx.x - off] : 0;
        __syncthreads();
        sh[threadIdx.x] += t;
        __syncthreads();
    }
    if ((int)threadIdx.x < nb) bsum[threadIdx.x] = sh[threadIdx.x] - v;
}

// colp[i] += bsum[block]; colp[N] = E; fill[i] = final colp[i]
__global__ __launch_bounds__(256) void k_scan_add(
    int* __restrict__ colp, const int* __restrict__ bsum,
    int* __restrict__ fill, int N, int E)
{
    int i = blockIdx.x * 256 + threadIdx.x;
    if (i < N) {
        int v = colp[i] + bsum[blockIdx.x];
        colp[i] = v;
        fill[i] = v;
    }
    if (i == 0) colp[N] = E;
}

// scatter edges into CSR slots: meta[slot] = (row, norm)
__global__ __launch_bounds__(256) void k_perm(
    const int* __restrict__ rows, const int* __restrict__ cols,
    const float* __restrict__ ew, const float* __restrict__ dis,
    int* __restrict__ fill, int2* __restrict__ meta, int E)
{
    int e = blockIdx.x * blockDim.x + threadIdx.x;
    if (e >= E) return;
    int r = rows[e], c = cols[e];
    float w = ew[e];
    w = (w > 0.0f) ? w : 1e-7f;
    float nm = dis[r] * w * dis[c];
    int slot = atomicAdd(&fill[c], 1);
    int2 m; m.x = r; m.y = __float_as_int(nm);
    meta[slot] = m;
}

// one wave per dst node: acc = dis^2*h[node] + sum norm*h[row] (+bias)
__global__ __launch_bounds__(256) void k_hop_gather(
    const int* __restrict__ colp, const int2* __restrict__ meta,
    const float* __restrict__ dis,
    const float* __restrict__ hin, const float* __restrict__ bias,
    float* __restrict__ hout, int N)
{
    const int wave = threadIdx.x >> 6;
    const int lane = threadIdx.x & 63;
    const int node = blockIdx.x * 4 + wave;
    if (node >= N) return;

    const int s = colp[node];
    const int t = colp[node + 1];
    const float d  = dis[node];
    const float d2 = d * d;

    const float2* hin2 = reinterpret_cast<const float2*>(hin);
    float2 v = hin2[(size_t)node * 64 + lane];
    float2 acc;
    acc.x = d2 * v.x;
    acc.y = d2 * v.y;

#pragma unroll 4
    for (int j = s; j < t; ++j) {
        int2 m = meta[j];                       // uniform across wave
        float nm = __int_as_float(m.y);
        float2 u = hin2[(size_t)m.x * 64 + lane];
        acc.x += nm * u.x;
        acc.y += nm * u.y;
    }
    if (bias) {
        float2 bv = reinterpret_cast<const float2*>(bias)[lane];
        acc.x += bv.x;
        acc.y += bv.y;
    }
    reinterpret_cast<float2*>(hout)[(size_t)node * 64 + lane] = acc;
}

extern "C" void kernel_launch(void* const* d_in, const int* in_sizes, int n_in,
                              void* d_out, int out_size, void* d_ws, size_t ws_size,
                              hipStream_t stream)
{
    const float* x  = (const float*)d_in[0];
    const int*   ei = (const int*)d_in[1];     // int32 (harness converts)
    const float* ew = (const float*)d_in[2];
    const float* W  = (const float*)d_in[3];
    const float* b  = (const float*)d_in[4];

    const int E  = in_sizes[2];
    const int H  = in_sizes[4];        // 128
    const int T  = in_sizes[3] / H;    // 256
    const int N  = in_sizes[0] / T;    // 50000

    const int* rows = ei;              // sources
    const int* cols = ei + E;          // targets (aggregation index)

    // ---- workspace layout (8B alignment for meta first) ----
    char* wsb = (char*)d_ws;
    float* h1    = (float*)wsb;                       wsb += (size_t)N * H * 4;  // 25.6 MB
    int2*  meta  = (int2*)wsb;                        wsb += (size_t)E * 8;      // 6.4 MB
    float* dis   = (float*)wsb;                       wsb += (size_t)N * 4;      // deg->dis in place
    int*   cnts  = (int*)wsb;                         wsb += (size_t)N * 4;
    int*   colp  = (int*)wsb;                         wsb += (size_t)(N + 1) * 4;
    int*   fill  = (int*)wsb;                         wsb += (size_t)N * 4;
    int*   bsum  = (int*)wsb;                         wsb += 1024 * 4;
    // total ~33 MB

    float* out = (float*)d_out;

    const int gN  = (N + 255) / 256;       // per-node grids
    const int gE  = (E + 255) / 256;       // per-edge grids
    const int nbS = (N + 255) / 256;       // scan blocks (<=1024 required)

    // 1. out <- X W^T
    k_transform<<<(N + 15) / 16, 128, 0, stream>>>(x, W, out, N);

    // 2. degree + histogram
    k_init<<<gN, 256, 0, stream>>>(dis, cnts, N);
    k_deg_count<<<gE, 256, 0, stream>>>(cols, ew, dis, cnts, E);
    k_dis<<<gN, 256, 0, stream>>>(dis, N);

    // 3. CSR: scan counts -> colp, then permute edges
    k_scan_partial<<<nbS, 256, 0, stream>>>(cnts, colp, bsum, N);
    k_scan_bsum<<<1, 1024, 0, stream>>>(bsum, nbS);
    k_scan_add<<<nbS, 256, 0, stream>>>(colp, bsum, fill, N, E);
    k_perm<<<gE, 256, 0, stream>>>(rows, cols, ew, dis, fill, meta, E);

    // 4. hops (atomic-free gather, one wave per node)
    const int gH = (N + 3) / 4;
    k_hop_gather<<<gH, 256, 0, stream>>>(colp, meta, dis, out, nullptr, h1, N);
    k_hop_gather<<<gH, 256, 0, stream>>>(colp, meta, dis, h1, b, out, N);
}

// Round 5
// 328.373 us; speedup vs baseline: 8.6618x; 1.0358x over previous
//
#include <hip/hip_runtime.h>

// ---------------------------------------------------------------------------
// SGConv (K=2): out = A^2 (X W^T) + b,  A = D^{-1/2}(Adj_clamped + I)D^{-1/2}
// N=50000, E=800000, T=256, H=128. edge_index arrives as int32.
//
// r5 = r4 + compile fix (ybf cast at transform call site).
// transform via bf16 MFMA (16x16x32), h-matrix in bf16, fp32 accumulation.
// ---------------------------------------------------------------------------

typedef __attribute__((ext_vector_type(8))) short short8_t;   // 8 bf16 (4 VGPR)
typedef __attribute__((ext_vector_type(4))) float f32x4_t;    // MFMA acc

__device__ inline unsigned short f2bf(float f) {               // RNE f32->bf16
    unsigned int u = __float_as_uint(f);
    return (unsigned short)((u + 0x7fffu + ((u >> 16) & 1u)) >> 16);
}
__device__ inline float bf_lo(unsigned int u) { return __uint_as_float(u << 16); }
__device__ inline float bf_hi(unsigned int u) { return __uint_as_float(u & 0xffff0000u); }

// ---- init: deg=1, counts=0, and convert W (WT elems) to bf16 ----
__global__ __launch_bounds__(256) void k_init(
    float* __restrict__ deg, int* __restrict__ counts, int N,
    const float* __restrict__ W, unsigned short* __restrict__ Wbf, int WT)
{
    int i = blockIdx.x * blockDim.x + threadIdx.x;
    if (i < N) { deg[i] = 1.0f; counts[i] = 0; }
    if (i < WT) Wbf[i] = f2bf(W[i]);
}

// ---- deg[col] += clamp(w); counts[col]++ ----
__global__ __launch_bounds__(256) void k_deg_count(
    const int* __restrict__ cols, const float* __restrict__ ew,
    float* __restrict__ deg, int* __restrict__ counts, int E)
{
    int e = blockIdx.x * blockDim.x + threadIdx.x;
    if (e >= E) return;
    float w = ew[e];
    w = (w > 0.0f) ? w : 1e-7f;          // elu(w)<=0 <=> w<=0
    int c = cols[e];
    atomicAdd(&deg[c], w);
    atomicAdd(&counts[c], 1);
}

// ---- y[r][h] = dot(x[r], W[h]) via MFMA bf16; y stored bf16 ----
// one wave per 16-row tile; K=256 in 8 steps; H=128 as 8 col-tiles.
__global__ __launch_bounds__(256) void k_transform_mfma(
    const float* __restrict__ x, const unsigned short* __restrict__ Wbf,
    unsigned short* __restrict__ y, int N)
{
    const int wid  = (blockIdx.x * blockDim.x + threadIdx.x) >> 6;
    const int lane = threadIdx.x & 63;
    const int r0   = wid * 16;
    if (r0 >= N) return;
    const int lr = lane & 15;     // A-row / B-col / D-col within tile
    const int kg = lane >> 4;     // k-group (8 consecutive k each)

    const float* xrow = x + (size_t)(r0 + lr) * 256;

    f32x4_t acc[8];
#pragma unroll
    for (int n = 0; n < 8; ++n) acc[n] = (f32x4_t){0.f, 0.f, 0.f, 0.f};

    for (int k0 = 0; k0 < 256; k0 += 32) {
        const int kb = k0 + kg * 8;
        float4 a0 = *reinterpret_cast<const float4*>(xrow + kb);
        float4 a1 = *reinterpret_cast<const float4*>(xrow + kb + 4);
        short8_t af;
        af[0] = (short)f2bf(a0.x); af[1] = (short)f2bf(a0.y);
        af[2] = (short)f2bf(a0.z); af[3] = (short)f2bf(a0.w);
        af[4] = (short)f2bf(a1.x); af[5] = (short)f2bf(a1.y);
        af[6] = (short)f2bf(a1.z); af[7] = (short)f2bf(a1.w);
#pragma unroll
        for (int n = 0; n < 8; ++n) {
            short8_t bf = *reinterpret_cast<const short8_t*>(
                Wbf + (size_t)(n * 16 + lr) * 256 + kb);
            acc[n] = __builtin_amdgcn_mfma_f32_16x16x32_bf16(af, bf, acc[n], 0, 0, 0);
        }
    }

    // D layout: col = lane&15, row = (lane>>4)*4 + reg   [verified m89/m91]
#pragma unroll
    for (int n = 0; n < 8; ++n) {
#pragma unroll
        for (int r = 0; r < 4; ++r) {
            const int orow = r0 + kg * 4 + r;
            y[(size_t)orow * 128 + n * 16 + lr] = f2bf(acc[n][r]);
        }
    }
}

// ---- fused: dis = rsqrt(deg) in place + per-block exclusive scan of counts ----
__global__ __launch_bounds__(256) void k_scan_partial(
    const int* __restrict__ counts, int* __restrict__ colp,
    int* __restrict__ bsum, float* __restrict__ deg, int N)
{
    __shared__ int sh[256];
    int i = blockIdx.x * 256 + threadIdx.x;
    if (i < N) deg[i] = rsqrtf(deg[i]);       // deg >= 1 always
    int v = (i < N) ? counts[i] : 0;
    sh[threadIdx.x] = v;
    __syncthreads();
    for (int off = 1; off < 256; off <<= 1) {
        int t = (threadIdx.x >= off) ? sh[threadIdx.x - off] : 0;
        __syncthreads();
        sh[threadIdx.x] += t;
        __syncthreads();
    }
    if (i < N) colp[i] = sh[threadIdx.x] - v;  // exclusive
    if (threadIdx.x == 255) bsum[blockIdx.x] = sh[255];
}

__global__ __launch_bounds__(1024) void k_scan_bsum(int* __restrict__ bsum, int nb)
{
    __shared__ int sh[1024];
    int v = ((int)threadIdx.x < nb) ? bsum[threadIdx.x] : 0;
    sh[threadIdx.x] = v;
    __syncthreads();
    for (int off = 1; off < 1024; off <<= 1) {
        int t = ((int)threadIdx.x >= off) ? sh[threadIdx.x - off] : 0;
        __syncthreads();
        sh[threadIdx.x] += t;
        __syncthreads();
    }
    if ((int)threadIdx.x < nb) bsum[threadIdx.x] = sh[threadIdx.x] - v;
}

__global__ __launch_bounds__(256) void k_scan_add(
    int* __restrict__ colp, const int* __restrict__ bsum,
    int* __restrict__ fill, int N, int E)
{
    int i = blockIdx.x * 256 + threadIdx.x;
    if (i < N) {
        int v = colp[i] + bsum[blockIdx.x];
        colp[i] = v;
        fill[i] = v;
    }
    if (i == 0) colp[N] = E;
}

// ---- scatter edges into CSR slots: meta[slot] = (row, norm) ----
__global__ __launch_bounds__(256) void k_perm(
    const int* __restrict__ rows, const int* __restrict__ cols,
    const float* __restrict__ ew, const float* __restrict__ dis,
    int* __restrict__ fill, int2* __restrict__ meta, int E)
{
    int e = blockIdx.x * blockDim.x + threadIdx.x;
    if (e >= E) return;
    int r = rows[e], c = cols[e];
    float w = ew[e];
    w = (w > 0.0f) ? w : 1e-7f;
    float nm = dis[r] * w * dis[c];
    int slot = atomicAdd(&fill[c], 1);
    int2 m; m.x = r; m.y = __float_as_int(nm);
    meta[slot] = m;
}

// ---- hop: one wave per dst node; bf16 rows (64 lanes x u32 = 2 bf16) ----
// acc = dis^2 * h[node] + sum norm * h[src];  OUT_F32: +bias, fp32 out.
template <bool OUT_F32>
__global__ __launch_bounds__(256) void k_hop_gather(
    const int* __restrict__ colp, const int2* __restrict__ meta,
    const float* __restrict__ dis, const unsigned int* __restrict__ hin,
    const float* __restrict__ bias, void* __restrict__ hout, int N)
{
    const int wave = threadIdx.x >> 6;
    const int lane = threadIdx.x & 63;
    const int node = blockIdx.x * 4 + wave;
    if (node >= N) return;

    const int s = colp[node];
    const int t = colp[node + 1];
    const float d  = dis[node];
    const float d2 = d * d;

    unsigned int v = hin[(size_t)node * 64 + lane];
    float2 acc;
    acc.x = d2 * bf_lo(v);
    acc.y = d2 * bf_hi(v);

    for (int j = s; j < t; ++j) {
        int2 m = meta[j];                        // wave-uniform broadcast
        float nm = __int_as_float(m.y);
        unsigned int u = hin[(size_t)m.x * 64 + lane];
        acc.x += nm * bf_lo(u);
        acc.y += nm * bf_hi(u);
    }

    if (OUT_F32) {
        float2 bv = reinterpret_cast<const float2*>(bias)[lane];
        acc.x += bv.x; acc.y += bv.y;
        reinterpret_cast<float2*>(hout)[(size_t)node * 64 + lane] = acc;
    } else {
        unsigned int p = (unsigned int)f2bf(acc.x) |
                         ((unsigned int)f2bf(acc.y) << 16);
        reinterpret_cast<unsigned int*>(hout)[(size_t)node * 64 + lane] = p;
    }
}

extern "C" void kernel_launch(void* const* d_in, const int* in_sizes, int n_in,
                              void* d_out, int out_size, void* d_ws, size_t ws_size,
                              hipStream_t stream)
{
    const float* x  = (const float*)d_in[0];
    const int*   ei = (const int*)d_in[1];     // int32 (harness converts)
    const float* ew = (const float*)d_in[2];
    const float* W  = (const float*)d_in[3];
    const float* b  = (const float*)d_in[4];

    const int E  = in_sizes[2];
    const int H  = in_sizes[4];        // 128
    const int T  = in_sizes[3] / H;    // 256
    const int N  = in_sizes[0] / T;    // 50000
    const int WT = in_sizes[3];        // 32768

    const int* rows = ei;              // sources
    const int* cols = ei + E;          // targets (aggregation index)

    // ---- workspace ----
    char* wsb = (char*)d_ws;
    unsigned int*   ybf  = (unsigned int*)wsb;   wsb += (size_t)N * (H / 2) * 4; // 12.8 MB
    unsigned int*   h1   = (unsigned int*)wsb;   wsb += (size_t)N * (H / 2) * 4; // 12.8 MB
    int2*           meta = (int2*)wsb;           wsb += (size_t)E * 8;           // 6.4 MB
    unsigned short* Wbf  = (unsigned short*)wsb; wsb += (size_t)WT * 2;          // 64 KB
    float*          dis  = (float*)wsb;          wsb += (size_t)N * 4;  // deg->dis in place
    int*            cnts = (int*)wsb;            wsb += (size_t)N * 4;
    int*            colp = (int*)wsb;            wsb += (size_t)(N + 1) * 4;
    int*            fill = (int*)wsb;            wsb += (size_t)N * 4;
    int*            bsum = (int*)wsb;            wsb += 1024 * 4;
    // total ~33 MB

    float* out = (float*)d_out;

    const int gN  = (N + 255) / 256;
    const int gE  = (E + 255) / 256;
    const int nbS = (N + 255) / 256;   // scan blocks (<=1024)

    // init (deg/cnts) + W->bf16
    k_init<<<gN, 256, 0, stream>>>(dis, cnts, N, W, Wbf, WT);
    // transform: ybf = bf16(X W^T)   (3125 waves)
    {
        int waves  = (N + 15) / 16;
        int blocks = (waves + 3) / 4;
        k_transform_mfma<<<blocks, 256, 0, stream>>>(
            x, Wbf, (unsigned short*)ybf, N);
    }
    // degree + histogram
    k_deg_count<<<gE, 256, 0, stream>>>(cols, ew, dis, cnts, E);
    // dis + CSR scan
    k_scan_partial<<<nbS, 256, 0, stream>>>(cnts, colp, bsum, dis, N);
    k_scan_bsum<<<1, 1024, 0, stream>>>(bsum, nbS);
    k_scan_add<<<nbS, 256, 0, stream>>>(colp, bsum, fill, N, E);
    k_perm<<<gE, 256, 0, stream>>>(rows, cols, ew, dis, fill, meta, E);

    // hops
    const int gH = (N + 3) / 4;
    k_hop_gather<false><<<gH, 256, 0, stream>>>(colp, meta, dis, ybf, nullptr, h1, N);
    k_hop_gather<true ><<<gH, 256, 0, stream>>>(colp, meta, dis, h1, b, out, N);
}

// Round 6
// 219.014 us; speedup vs baseline: 12.9869x; 1.4993x over previous
//
#include <hip/hip_runtime.h>

// ---------------------------------------------------------------------------
// SGConv (K=2): out = A^2 (X W^T) + b,  A = D^{-1/2}(Adj_clamped + I)D^{-1/2}
// N=50000, E=800000, T=256, H=128. edge_index arrives as int32.
//
// r6: z-form (z = dis*y, meta stores raw clamped w), unroll-4 gather hop,
// CSR build slimmed (int-only histogram, no dis gathers in perm).
// Pipeline: memset cnts -> count(+Wbf) -> scan -> perm -> dis -> transform(z)
//           -> hop1 (z1 = bf16(dis^2*(z[c]+sum w z[r])))
//           -> hop2 (out = dis*(z1[c]+sum w z1[r]) + b)
// ---------------------------------------------------------------------------

typedef __attribute__((ext_vector_type(8))) short short8_t;   // 8 bf16
typedef __attribute__((ext_vector_type(4))) float f32x4_t;    // MFMA acc

__device__ inline unsigned short f2bf(float f) {               // RNE f32->bf16
    unsigned int u = __float_as_uint(f);
    return (unsigned short)((u + 0x7fffu + ((u >> 16) & 1u)) >> 16);
}
__device__ inline float bf_lo(unsigned int u) { return __uint_as_float(u << 16); }
__device__ inline float bf_hi(unsigned int u) { return __uint_as_float(u & 0xffff0000u); }

// ---- histogram cnts[col]++ ; first WT threads also convert W -> bf16 ----
__global__ __launch_bounds__(256) void k_count(
    const int* __restrict__ cols, int* __restrict__ cnts, int E,
    const float* __restrict__ W, unsigned short* __restrict__ Wbf, int WT)
{
    int e = blockIdx.x * blockDim.x + threadIdx.x;
    if (e < WT) Wbf[e] = f2bf(W[e]);
    if (e >= E) return;
    atomicAdd(&cnts[cols[e]], 1);
}

// ---- per-block exclusive scan of cnts -> colp, block totals -> bsum ----
__global__ __launch_bounds__(256) void k_scan_partial(
    const int* __restrict__ cnts, int* __restrict__ colp,
    int* __restrict__ bsum, int N)
{
    __shared__ int sh[256];
    int i = blockIdx.x * 256 + threadIdx.x;
    int v = (i < N) ? cnts[i] : 0;
    sh[threadIdx.x] = v;
    __syncthreads();
    for (int off = 1; off < 256; off <<= 1) {
        int t = (threadIdx.x >= off) ? sh[threadIdx.x - off] : 0;
        __syncthreads();
        sh[threadIdx.x] += t;
        __syncthreads();
    }
    if (i < N) colp[i] = sh[threadIdx.x] - v;  // exclusive
    if (threadIdx.x == 255) bsum[blockIdx.x] = sh[255];
}

__global__ __launch_bounds__(1024) void k_scan_bsum(int* __restrict__ bsum, int nb)
{
    __shared__ int sh[1024];
    int v = ((int)threadIdx.x < nb) ? bsum[threadIdx.x] : 0;
    sh[threadIdx.x] = v;
    __syncthreads();
    for (int off = 1; off < 1024; off <<= 1) {
        int t = ((int)threadIdx.x >= off) ? sh[threadIdx.x - off] : 0;
        __syncthreads();
        sh[threadIdx.x] += t;
        __syncthreads();
    }
    if ((int)threadIdx.x < nb) bsum[threadIdx.x] = sh[threadIdx.x] - v;
}

__global__ __launch_bounds__(256) void k_scan_add(
    int* __restrict__ colp, const int* __restrict__ bsum,
    int* __restrict__ fill, int N, int E)
{
    int i = blockIdx.x * 256 + threadIdx.x;
    if (i < N) {
        int v = colp[i] + bsum[blockIdx.x];
        colp[i] = v;
        fill[i] = v;
    }
    if (i == 0) colp[N] = E;
}

// ---- scatter edges into CSR slots: meta[slot] = (row, clamped w) ----
__global__ __launch_bounds__(256) void k_perm(
    const int* __restrict__ rows, const int* __restrict__ cols,
    const float* __restrict__ ew,
    int* __restrict__ fill, int2* __restrict__ meta, int E)
{
    int e = blockIdx.x * blockDim.x + threadIdx.x;
    if (e >= E) return;
    float w = ew[e];
    w = (w > 0.0f) ? w : 1e-7f;          // elu(w)<=0 <=> w<=0
    int slot = atomicAdd(&fill[cols[e]], 1);
    int2 m; m.x = rows[e]; m.y = __float_as_int(w);
    meta[slot] = m;
}

// ---- dis[i] = rsqrt(1 + sum of w over CSR range) ----
__global__ __launch_bounds__(256) void k_dis(
    const int* __restrict__ colp, const int2* __restrict__ meta,
    float* __restrict__ dis, int N)
{
    int i = blockIdx.x * blockDim.x + threadIdx.x;
    if (i >= N) return;
    int s = colp[i], t = colp[i + 1];
    float sum = 1.0f;                    // self-loop
    for (int j = s; j < t; ++j) sum += __int_as_float(meta[j].y);
    dis[i] = rsqrtf(sum);
}

// ---- z[r][h] = bf16( dis[r] * dot(x[r], W[h]) ) via MFMA bf16 ----
__global__ __launch_bounds__(256) void k_transform_mfma(
    const float* __restrict__ x, const unsigned short* __restrict__ Wbf,
    const float* __restrict__ dis, unsigned short* __restrict__ z, int N)
{
    const int wid  = (blockIdx.x * blockDim.x + threadIdx.x) >> 6;
    const int lane = threadIdx.x & 63;
    const int r0   = wid * 16;
    if (r0 >= N) return;
    const int lr = lane & 15;
    const int kg = lane >> 4;

    const float* xrow = x + (size_t)(r0 + lr) * 256;

    f32x4_t acc[8];
#pragma unroll
    for (int n = 0; n < 8; ++n) acc[n] = (f32x4_t){0.f, 0.f, 0.f, 0.f};

    for (int k0 = 0; k0 < 256; k0 += 32) {
        const int kb = k0 + kg * 8;
        float4 a0 = *reinterpret_cast<const float4*>(xrow + kb);
        float4 a1 = *reinterpret_cast<const float4*>(xrow + kb + 4);
        short8_t af;
        af[0] = (short)f2bf(a0.x); af[1] = (short)f2bf(a0.y);
        af[2] = (short)f2bf(a0.z); af[3] = (short)f2bf(a0.w);
        af[4] = (short)f2bf(a1.x); af[5] = (short)f2bf(a1.y);
        af[6] = (short)f2bf(a1.z); af[7] = (short)f2bf(a1.w);
#pragma unroll
        for (int n = 0; n < 8; ++n) {
            short8_t bf = *reinterpret_cast<const short8_t*>(
                Wbf + (size_t)(n * 16 + lr) * 256 + kb);
            acc[n] = __builtin_amdgcn_mfma_f32_16x16x32_bf16(af, bf, acc[n], 0, 0, 0);
        }
    }

    float dsc[4];
#pragma unroll
    for (int r = 0; r < 4; ++r) dsc[r] = dis[r0 + kg * 4 + r];

    // D layout: col = lane&15, row = (lane>>4)*4 + reg   [m89/m91]
#pragma unroll
    for (int n = 0; n < 8; ++n) {
#pragma unroll
        for (int r = 0; r < 4; ++r) {
            const int orow = r0 + kg * 4 + r;
            z[(size_t)orow * 128 + n * 16 + lr] = f2bf(dsc[r] * acc[n][r]);
        }
    }
}

// ---- hop: one wave per dst node, unroll-4 independent gathers ----
// acc = z[c] + sum w*z[r];  FINAL: out=dis*acc+bias (f32); else bf16(dis^2*acc)
template <bool FINAL>
__global__ __launch_bounds__(256) void k_hop(
    const int* __restrict__ colp, const int2* __restrict__ meta,
    const float* __restrict__ dis, const unsigned int* __restrict__ hin,
    const float* __restrict__ bias, void* __restrict__ hout, int N)
{
    const int wave = threadIdx.x >> 6;
    const int lane = threadIdx.x & 63;
    const int node = blockIdx.x * 4 + wave;
    if (node >= N) return;

    const int s = __builtin_amdgcn_readfirstlane(colp[node]);
    const int t = __builtin_amdgcn_readfirstlane(colp[node + 1]);
    const float d = dis[node];

    unsigned int v = hin[(size_t)node * 64 + lane];
    float ax = bf_lo(v), ay = bf_hi(v);            // self term z[c]

    int j = s;
    for (; j + 4 <= t; j += 4) {
        int2 m0 = meta[j];
        int2 m1 = meta[j + 1];
        int2 m2 = meta[j + 2];
        int2 m3 = meta[j + 3];
        unsigned int u0 = hin[(size_t)m0.x * 64 + lane];
        unsigned int u1 = hin[(size_t)m1.x * 64 + lane];
        unsigned int u2 = hin[(size_t)m2.x * 64 + lane];
        unsigned int u3 = hin[(size_t)m3.x * 64 + lane];
        const float w0 = __int_as_float(m0.y), w1 = __int_as_float(m1.y);
        const float w2 = __int_as_float(m2.y), w3 = __int_as_float(m3.y);
        ax += w0 * bf_lo(u0); ay += w0 * bf_hi(u0);
        ax += w1 * bf_lo(u1); ay += w1 * bf_hi(u1);
        ax += w2 * bf_lo(u2); ay += w2 * bf_hi(u2);
        ax += w3 * bf_lo(u3); ay += w3 * bf_hi(u3);
    }
    for (; j < t; ++j) {
        int2 m = meta[j];
        const float w = __int_as_float(m.y);
        unsigned int u = hin[(size_t)m.x * 64 + lane];
        ax += w * bf_lo(u); ay += w * bf_hi(u);
    }

    if (FINAL) {
        float2 bv = reinterpret_cast<const float2*>(bias)[lane];
        float2 o; o.x = d * ax + bv.x; o.y = d * ay + bv.y;
        reinterpret_cast<float2*>(hout)[(size_t)node * 64 + lane] = o;
    } else {
        const float d2 = d * d;
        unsigned int p = (unsigned int)f2bf(d2 * ax) |
                         ((unsigned int)f2bf(d2 * ay) << 16);
        reinterpret_cast<unsigned int*>(hout)[(size_t)node * 64 + lane] = p;
    }
}

extern "C" void kernel_launch(void* const* d_in, const int* in_sizes, int n_in,
                              void* d_out, int out_size, void* d_ws, size_t ws_size,
                              hipStream_t stream)
{
    const float* x  = (const float*)d_in[0];
    const int*   ei = (const int*)d_in[1];     // int32 (harness converts)
    const float* ew = (const float*)d_in[2];
    const float* W  = (const float*)d_in[3];
    const float* b  = (const float*)d_in[4];

    const int E  = in_sizes[2];
    const int H  = in_sizes[4];        // 128
    const int T  = in_sizes[3] / H;    // 256
    const int N  = in_sizes[0] / T;    // 50000
    const int WT = in_sizes[3];        // 32768

    const int* rows = ei;              // sources
    const int* cols = ei + E;          // targets (aggregation index)

    // ---- workspace ----
    char* wsb = (char*)d_ws;
    unsigned int*   z    = (unsigned int*)wsb;   wsb += (size_t)N * (H / 2) * 4; // 12.8 MB
    unsigned int*   z1   = (unsigned int*)wsb;   wsb += (size_t)N * (H / 2) * 4; // 12.8 MB
    int2*           meta = (int2*)wsb;           wsb += (size_t)E * 8;           // 6.4 MB
    unsigned short* Wbf  = (unsigned short*)wsb; wsb += (size_t)WT * 2;          // 64 KB
    float*          dis  = (float*)wsb;          wsb += (size_t)N * 4;
    int*            cnts = (int*)wsb;            wsb += (size_t)N * 4;
    int*            colp = (int*)wsb;            wsb += (size_t)(N + 1) * 4;
    int*            fill = (int*)wsb;            wsb += (size_t)N * 4;
    int*            bsum = (int*)wsb;            wsb += 1024 * 4;
    // total ~33 MB

    float* out = (float*)d_out;

    const int gN  = (N + 255) / 256;
    const int gE  = (E + 255) / 256;
    const int nbS = (N + 255) / 256;   // scan blocks (<=1024)

    // CSR build
    hipMemsetAsync(cnts, 0, (size_t)N * 4, stream);
    k_count<<<gE, 256, 0, stream>>>(cols, cnts, E, W, Wbf, WT);
    k_scan_partial<<<nbS, 256, 0, stream>>>(cnts, colp, bsum, N);
    k_scan_bsum<<<1, 1024, 0, stream>>>(bsum, nbS);
    k_scan_add<<<nbS, 256, 0, stream>>>(colp, bsum, fill, N, E);
    k_perm<<<gE, 256, 0, stream>>>(rows, cols, ew, fill, meta, E);
    k_dis<<<gN, 256, 0, stream>>>(colp, meta, dis, N);

    // transform: z = bf16(dis * (X W^T))
    {
        int waves  = (N + 15) / 16;
        int blocks = (waves + 3) / 4;
        k_transform_mfma<<<blocks, 256, 0, stream>>>(
            x, Wbf, dis, (unsigned short*)z, N);
    }

    // hops
    const int gH = (N + 3) / 4;
    k_hop<false><<<gH, 256, 0, stream>>>(colp, meta, dis, z, nullptr, z1, N);
    k_hop<true ><<<gH, 256, 0, stream>>>(colp, meta, dis, z1, b, out, N);
}

// Round 7
// 210.868 us; speedup vs baseline: 13.4886x; 1.0386x over previous
//
#include <hip/hip_runtime.h>

// ---------------------------------------------------------------------------
// SGConv (K=2): out = A^2 (X W^T) + b,  A = D^{-1/2}(Adj_clamped + I)D^{-1/2}
// N=50000, E=800000, T=256, H=128. edge_index arrives as int32.
//
// r7: 4-byte meta records (row:16 | bf16(w):16  -- valid since N < 65536),
// single offsets array (scan->starts, perm bumps to ends), hop unroll-8.
// Pipeline: memset cnts -> count(+Wbf) -> scan -> perm -> dis -> transform(z)
//           -> hop1 (z1 = bf16(dis^2*(z[c]+sum w z[r])))
//           -> hop2 (out = dis*(z1[c]+sum w z1[r]) + b)
// ---------------------------------------------------------------------------

typedef __attribute__((ext_vector_type(8))) short short8_t;   // 8 bf16
typedef __attribute__((ext_vector_type(4))) float f32x4_t;    // MFMA acc

__device__ inline unsigned short f2bf(float f) {               // RNE f32->bf16
    unsigned int u = __float_as_uint(f);
    return (unsigned short)((u + 0x7fffu + ((u >> 16) & 1u)) >> 16);
}
__device__ inline float bf_lo(unsigned int u) { return __uint_as_float(u << 16); }
__device__ inline float bf_hi(unsigned int u) { return __uint_as_float(u & 0xffff0000u); }

// ---- histogram cnts[col]++ ; first WT threads also convert W -> bf16 ----
__global__ __launch_bounds__(256) void k_count(
    const int* __restrict__ cols, int* __restrict__ cnts, int E,
    const float* __restrict__ W, unsigned short* __restrict__ Wbf, int WT)
{
    int e = blockIdx.x * blockDim.x + threadIdx.x;
    if (e < WT) Wbf[e] = f2bf(W[e]);
    if (e >= E) return;
    atomicAdd(&cnts[cols[e]], 1);
}

// ---- per-block exclusive scan of cnts -> offs, block totals -> bsum ----
__global__ __launch_bounds__(256) void k_scan_partial(
    const int* __restrict__ cnts, int* __restrict__ offs,
    int* __restrict__ bsum, int N)
{
    __shared__ int sh[256];
    int i = blockIdx.x * 256 + threadIdx.x;
    int v = (i < N) ? cnts[i] : 0;
    sh[threadIdx.x] = v;
    __syncthreads();
    for (int off = 1; off < 256; off <<= 1) {
        int t = (threadIdx.x >= off) ? sh[threadIdx.x - off] : 0;
        __syncthreads();
        sh[threadIdx.x] += t;
        __syncthreads();
    }
    if (i < N) offs[i] = sh[threadIdx.x] - v;  // exclusive (start offsets)
    if (threadIdx.x == 255) bsum[blockIdx.x] = sh[255];
}

__global__ __launch_bounds__(1024) void k_scan_bsum(int* __restrict__ bsum, int nb)
{
    __shared__ int sh[1024];
    int v = ((int)threadIdx.x < nb) ? bsum[threadIdx.x] : 0;
    sh[threadIdx.x] = v;
    __syncthreads();
    for (int off = 1; off < 1024; off <<= 1) {
        int t = ((int)threadIdx.x >= off) ? sh[threadIdx.x - off] : 0;
        __syncthreads();
        sh[threadIdx.x] += t;
        __syncthreads();
    }
    if ((int)threadIdx.x < nb) bsum[threadIdx.x] = sh[threadIdx.x] - v;
}

// offs[i] += bsum[block]  (in place; offs stays = start offsets)
__global__ __launch_bounds__(256) void k_scan_add(
    int* __restrict__ offs, const int* __restrict__ bsum, int N)
{
    int i = blockIdx.x * 256 + threadIdx.x;
    if (i < N) offs[i] += bsum[blockIdx.x];
}

// ---- scatter edges into CSR slots: meta[slot] = bf16(w)<<16 | row ----
// offs is bumped from start offsets to END offsets by the atomics.
__global__ __launch_bounds__(256) void k_perm(
    const int* __restrict__ rows, const int* __restrict__ cols,
    const float* __restrict__ ew,
    int* __restrict__ offs, unsigned int* __restrict__ meta, int E)
{
    int e = blockIdx.x * blockDim.x + threadIdx.x;
    if (e >= E) return;
    float w = ew[e];
    w = (w > 0.0f) ? w : 1e-7f;          // elu(w)<=0 <=> w<=0
    int slot = atomicAdd(&offs[cols[e]], 1);
    meta[slot] = ((unsigned int)f2bf(w) << 16) | (unsigned int)rows[e];
}

// ---- dis[i] = rsqrt(1 + sum of w over CSR range [ends[i-1], ends[i]) ) ----
__global__ __launch_bounds__(256) void k_dis(
    const int* __restrict__ ends, const unsigned int* __restrict__ meta,
    float* __restrict__ dis, int N)
{
    int i = blockIdx.x * blockDim.x + threadIdx.x;
    if (i >= N) return;
    int s = (i > 0) ? ends[i - 1] : 0;
    int t = ends[i];
    float sum = 1.0f;                    // self-loop
    for (int j = s; j < t; ++j) sum += bf_hi(meta[j]);
    dis[i] = rsqrtf(sum);
}

// ---- z[r][h] = bf16( dis[r] * dot(x[r], W[h]) ) via MFMA bf16 ----
__global__ __launch_bounds__(256) void k_transform_mfma(
    const float* __restrict__ x, const unsigned short* __restrict__ Wbf,
    const float* __restrict__ dis, unsigned short* __restrict__ z, int N)
{
    const int wid  = (blockIdx.x * blockDim.x + threadIdx.x) >> 6;
    const int lane = threadIdx.x & 63;
    const int r0   = wid * 16;
    if (r0 >= N) return;
    const int lr = lane & 15;
    const int kg = lane >> 4;

    const float* xrow = x + (size_t)(r0 + lr) * 256;

    f32x4_t acc[8];
#pragma unroll
    for (int n = 0; n < 8; ++n) acc[n] = (f32x4_t){0.f, 0.f, 0.f, 0.f};

    for (int k0 = 0; k0 < 256; k0 += 32) {
        const int kb = k0 + kg * 8;
        float4 a0 = *reinterpret_cast<const float4*>(xrow + kb);
        float4 a1 = *reinterpret_cast<const float4*>(xrow + kb + 4);
        short8_t af;
        af[0] = (short)f2bf(a0.x); af[1] = (short)f2bf(a0.y);
        af[2] = (short)f2bf(a0.z); af[3] = (short)f2bf(a0.w);
        af[4] = (short)f2bf(a1.x); af[5] = (short)f2bf(a1.y);
        af[6] = (short)f2bf(a1.z); af[7] = (short)f2bf(a1.w);
#pragma unroll
        for (int n = 0; n < 8; ++n) {
            short8_t bf = *reinterpret_cast<const short8_t*>(
                Wbf + (size_t)(n * 16 + lr) * 256 + kb);
            acc[n] = __builtin_amdgcn_mfma_f32_16x16x32_bf16(af, bf, acc[n], 0, 0, 0);
        }
    }

    float dsc[4];
#pragma unroll
    for (int r = 0; r < 4; ++r) dsc[r] = dis[r0 + kg * 4 + r];

    // D layout: col = lane&15, row = (lane>>4)*4 + reg   [m89/m91]
#pragma unroll
    for (int n = 0; n < 8; ++n) {
#pragma unroll
        for (int r = 0; r < 4; ++r) {
            const int orow = r0 + kg * 4 + r;
            z[(size_t)orow * 128 + n * 16 + lr] = f2bf(dsc[r] * acc[n][r]);
        }
    }
}

// ---- hop: one wave per dst node, unroll-8 independent gathers ----
// acc = z[c] + sum w*z[r];  FINAL: out=dis*acc+bias (f32); else bf16(dis^2*acc)
template <bool FINAL>
__global__ __launch_bounds__(256) void k_hop(
    const int* __restrict__ ends, const unsigned int* __restrict__ meta,
    const float* __restrict__ dis, const unsigned int* __restrict__ hin,
    const float* __restrict__ bias, void* __restrict__ hout, int N)
{
    const int wave = threadIdx.x >> 6;
    const int lane = threadIdx.x & 63;
    const int node = blockIdx.x * 4 + wave;
    if (node >= N) return;

    const int s = __builtin_amdgcn_readfirstlane((node > 0) ? ends[node - 1] : 0);
    const int t = __builtin_amdgcn_readfirstlane(ends[node]);
    const float d = dis[node];

    unsigned int v = hin[(size_t)node * 64 + lane];
    float ax = bf_lo(v), ay = bf_hi(v);            // self term z[c]

    int j = s;
    for (; j + 8 <= t; j += 8) {
        unsigned int m0 = meta[j],     m1 = meta[j + 1];
        unsigned int m2 = meta[j + 2], m3 = meta[j + 3];
        unsigned int m4 = meta[j + 4], m5 = meta[j + 5];
        unsigned int m6 = meta[j + 6], m7 = meta[j + 7];
        unsigned int u0 = hin[(size_t)(m0 & 0xffffu) * 64 + lane];
        unsigned int u1 = hin[(size_t)(m1 & 0xffffu) * 64 + lane];
        unsigned int u2 = hin[(size_t)(m2 & 0xffffu) * 64 + lane];
        unsigned int u3 = hin[(size_t)(m3 & 0xffffu) * 64 + lane];
        unsigned int u4 = hin[(size_t)(m4 & 0xffffu) * 64 + lane];
        unsigned int u5 = hin[(size_t)(m5 & 0xffffu) * 64 + lane];
        unsigned int u6 = hin[(size_t)(m6 & 0xffffu) * 64 + lane];
        unsigned int u7 = hin[(size_t)(m7 & 0xffffu) * 64 + lane];
        ax += bf_hi(m0) * bf_lo(u0); ay += bf_hi(m0) * bf_hi(u0);
        ax += bf_hi(m1) * bf_lo(u1); ay += bf_hi(m1) * bf_hi(u1);
        ax += bf_hi(m2) * bf_lo(u2); ay += bf_hi(m2) * bf_hi(u2);
        ax += bf_hi(m3) * bf_lo(u3); ay += bf_hi(m3) * bf_hi(u3);
        ax += bf_hi(m4) * bf_lo(u4); ay += bf_hi(m4) * bf_hi(u4);
        ax += bf_hi(m5) * bf_lo(u5); ay += bf_hi(m5) * bf_hi(u5);
        ax += bf_hi(m6) * bf_lo(u6); ay += bf_hi(m6) * bf_hi(u6);
        ax += bf_hi(m7) * bf_lo(u7); ay += bf_hi(m7) * bf_hi(u7);
    }
    for (; j < t; ++j) {
        unsigned int m = meta[j];
        const float w = bf_hi(m);
        unsigned int u = hin[(size_t)(m & 0xffffu) * 64 + lane];
        ax += w * bf_lo(u); ay += w * bf_hi(u);
    }

    if (FINAL) {
        float2 bv = reinterpret_cast<const float2*>(bias)[lane];
        float2 o; o.x = d * ax + bv.x; o.y = d * ay + bv.y;
        reinterpret_cast<float2*>(hout)[(size_t)node * 64 + lane] = o;
    } else {
        const float d2 = d * d;
        unsigned int p = (unsigned int)f2bf(d2 * ax) |
                         ((unsigned int)f2bf(d2 * ay) << 16);
        reinterpret_cast<unsigned int*>(hout)[(size_t)node * 64 + lane] = p;
    }
}

extern "C" void kernel_launch(void* const* d_in, const int* in_sizes, int n_in,
                              void* d_out, int out_size, void* d_ws, size_t ws_size,
                              hipStream_t stream)
{
    const float* x  = (const float*)d_in[0];
    const int*   ei = (const int*)d_in[1];     // int32 (harness converts)
    const float* ew = (const float*)d_in[2];
    const float* W  = (const float*)d_in[3];
    const float* b  = (const float*)d_in[4];

    const int E  = in_sizes[2];
    const int H  = in_sizes[4];        // 128
    const int T  = in_sizes[3] / H;    // 256
    const int N  = in_sizes[0] / T;    // 50000  (< 65536: 16-bit rows valid)
    const int WT = in_sizes[3];        // 32768

    const int* rows = ei;              // sources
    const int* cols = ei + E;          // targets (aggregation index)

    // ---- workspace ----
    char* wsb = (char*)d_ws;
    unsigned int*   z    = (unsigned int*)wsb;   wsb += (size_t)N * (H / 2) * 4; // 12.8 MB
    unsigned int*   z1   = (unsigned int*)wsb;   wsb += (size_t)N * (H / 2) * 4; // 12.8 MB
    unsigned int*   meta = (unsigned int*)wsb;   wsb += (size_t)E * 4;           // 3.2 MB
    unsigned short* Wbf  = (unsigned short*)wsb; wsb += (size_t)WT * 2;          // 64 KB
    float*          dis  = (float*)wsb;          wsb += (size_t)N * 4;
    int*            cnts = (int*)wsb;            wsb += (size_t)N * 4;
    int*            offs = (int*)wsb;            wsb += (size_t)N * 4;  // starts->ends
    int*            bsum = (int*)wsb;            wsb += 1024 * 4;
    // total ~30 MB

    float* out = (float*)d_out;

    const int gN  = (N + 255) / 256;
    const int gE  = (E + 255) / 256;
    const int nbS = (N + 255) / 256;   // scan blocks (<=1024)

    // CSR build
    hipMemsetAsync(cnts, 0, (size_t)N * 4, stream);
    k_count<<<gE, 256, 0, stream>>>(cols, cnts, E, W, Wbf, WT);
    k_scan_partial<<<nbS, 256, 0, stream>>>(cnts, offs, bsum, N);
    k_scan_bsum<<<1, 1024, 0, stream>>>(bsum, nbS);
    k_scan_add<<<nbS, 256, 0, stream>>>(offs, bsum, N);
    k_perm<<<gE, 256, 0, stream>>>(rows, cols, ew, offs, meta, E);  // offs -> ends
    k_dis<<<gN, 256, 0, stream>>>(offs, meta, dis, N);

    // transform: z = bf16(dis * (X W^T))
    {
        int waves  = (N + 15) / 16;
        int blocks = (waves + 3) / 4;
        k_transform_mfma<<<blocks, 256, 0, stream>>>(
            x, Wbf, dis, (unsigned short*)z, N);
    }

    // hops
    const int gH = (N + 3) / 4;
    k_hop<false><<<gH, 256, 0, stream>>>(offs, meta, dis, z, nullptr, z1, N);
    k_hop<true ><<<gH, 256, 0, stream>>>(offs, meta, dis, z1, b, out, N);
}

// Round 8
// 138.965 us; speedup vs baseline: 20.4679x; 1.5174x over previous
//
#include <hip/hip_runtime.h>

// ---------------------------------------------------------------------------
// SGConv (K=2): out = A^2 (X W^T) + b,  A = D^{-1/2}(Adj_clamped + I)D^{-1/2}
// N=50000, E=800000, T=256, H=128. edge_index arrives as int32.
//
// r8: CSR build via two-pass bucket sort (no global random scatter):
//   passA: LDS-bin 4096-edge chunks by col>>8, one atomic per bucket/block,
//          append runs to per-bucket storage (aliased over z1).
//   passB: one block per bucket: LDS sort by node, coalesced meta write,
//          computes dis/starts/ends in-LDS (replaces count/scan/perm/dis).
// Then: transform(z = bf16(dis*XW^T)) -> hop1 -> hop2 (unroll-8 gathers).
// ---------------------------------------------------------------------------

typedef __attribute__((ext_vector_type(8))) short short8_t;   // 8 bf16
typedef __attribute__((ext_vector_type(4))) float f32x4_t;    // MFMA acc

constexpr int BK    = 256;   // nodes per bucket
constexpr int CAP   = 8192;  // records per bucket (mean 4096 + 64 sigma)
constexpr int CHUNK = 4096;  // edges per passA block

__device__ inline unsigned short f2bf(float f) {               // RNE f32->bf16
    unsigned int u = __float_as_uint(f);
    return (unsigned short)((u + 0x7fffu + ((u >> 16) & 1u)) >> 16);
}
__device__ inline float bf_lo(unsigned int u) { return __uint_as_float(u << 16); }
__device__ inline float bf_hi(unsigned int u) { return __uint_as_float(u & 0xffff0000u); }

// ---- passA: bucket-bin edges; coalesced appends to bucket storage ----
__global__ __launch_bounds__(256) void k_passA(
    const int* __restrict__ rows, const int* __restrict__ cols,
    const float* __restrict__ ew, int E,
    unsigned int* __restrict__ bwr,   // [NB*CAP]  w<<16|row
    unsigned char* __restrict__ bcl,  // [NB*CAP]  col low byte
    int* __restrict__ tails,          // [NB]
    const float* __restrict__ W, unsigned short* __restrict__ Wbf, int WT)
{
    const int tid = threadIdx.x;
    const int gid = blockIdx.x * 256 + tid;
    if (gid < WT) Wbf[gid] = f2bf(W[gid]);       // fold W->bf16 conversion

    __shared__ unsigned short lcol[CHUNK], lrow[CHUNK], lw[CHUNK];
    __shared__ unsigned short sidx[CHUNK];
    __shared__ int hist[256], lofs[256], fill[256], gbase[256];

    const int e0  = blockIdx.x * CHUNK;
    const int cnt = min(CHUNK, E - e0);
    if (cnt <= 0) return;

    hist[tid] = 0; fill[tid] = 0;
    __syncthreads();

    for (int i = tid; i < cnt; i += 256) {
        const int c = cols[e0 + i];
        const int r = rows[e0 + i];
        float w = ew[e0 + i];
        w = (w > 0.0f) ? w : 1e-7f;              // elu(w)<=0 <=> w<=0
        lcol[i] = (unsigned short)c;
        lrow[i] = (unsigned short)r;
        lw[i]   = f2bf(w);
        atomicAdd(&hist[c >> 8], 1);
    }
    __syncthreads();

    // exclusive scan of hist -> lofs
    {
        const int v = hist[tid];
        lofs[tid] = v;
        __syncthreads();
        for (int off = 1; off < 256; off <<= 1) {
            int t = (tid >= off) ? lofs[tid - off] : 0;
            __syncthreads();
            lofs[tid] += t;
            __syncthreads();
        }
        const int excl = lofs[tid] - v;
        __syncthreads();
        lofs[tid] = excl;
        __syncthreads();
    }

    // rank within block -> sorted index
    for (int i = tid; i < cnt; i += 256) {
        const int b = lcol[i] >> 8;
        const int pos = lofs[b] + atomicAdd(&fill[b], 1);
        sidx[pos] = (unsigned short)i;
    }
    __syncthreads();

    // reserve global space: one atomic per non-empty bucket
    {
        const int h = hist[tid];
        gbase[tid] = (h > 0) ? atomicAdd(&tails[tid], h) : 0;
    }
    __syncthreads();

    // write out in bucket-sorted order (runs of consecutive addresses)
    for (int i = tid; i < cnt; i += 256) {
        const int e = sidx[i];
        const int b = lcol[e] >> 8;
        const int slot = gbase[b] + (i - lofs[b]);
        if (slot < CAP) {                         // overflow guard
            const int addr = b * CAP + slot;
            bwr[addr] = ((unsigned int)lw[e] << 16) | lrow[e];
            bcl[addr] = (unsigned char)(lcol[e] & 255);
        }
    }
}

// ---- passB: per-bucket LDS sort + dis/starts/ends; coalesced meta write ----
__global__ __launch_bounds__(256) void k_passB(
    const unsigned int* __restrict__ bwr, const unsigned char* __restrict__ bcl,
    const int* __restrict__ tails,
    unsigned int* __restrict__ meta, int* __restrict__ starts,
    int* __restrict__ ends, float* __restrict__ dis, int N)
{
    const int tid  = threadIdx.x;
    const int b    = blockIdx.x;
    const int base = b * CAP;
    const int cnt  = min(tails[b], CAP);

    __shared__ unsigned int  lwr[CAP];      // 32 KB
    __shared__ unsigned char lcl[CAP];      // 8 KB
    __shared__ unsigned int  srt[CAP];      // 32 KB
    __shared__ int hist[256], offs[256], fill[256];

    hist[tid] = 0; fill[tid] = 0;
    __syncthreads();

    for (int i = tid; i < cnt; i += 256) {
        lwr[i] = bwr[base + i];
        unsigned char c = bcl[base + i];
        lcl[i] = c;
        atomicAdd(&hist[c], 1);
    }
    __syncthreads();

    // exclusive scan of hist -> offs
    {
        const int v = hist[tid];
        offs[tid] = v;
        __syncthreads();
        for (int off = 1; off < 256; off <<= 1) {
            int t = (tid >= off) ? offs[tid - off] : 0;
            __syncthreads();
            offs[tid] += t;
            __syncthreads();
        }
        const int excl = offs[tid] - v;
        __syncthreads();
        offs[tid] = excl;
        __syncthreads();
    }

    // scatter to sorted order (LDS -> LDS)
    for (int i = tid; i < cnt; i += 256) {
        const int c = lcl[i];
        const int pos = offs[c] + atomicAdd(&fill[c], 1);
        srt[pos] = lwr[i];
    }
    __syncthreads();

    // coalesced meta write
    for (int i = tid; i < cnt; i += 256) meta[base + i] = srt[i];

    // per-node: dis = rsqrt(1 + sum w), starts/ends
    const int node = b * BK + tid;
    if (node < N) {
        const int s = offs[tid];
        const int t = s + hist[tid];
        float sum = 1.0f;                         // self-loop
        for (int j = s; j < t; ++j) sum += bf_hi(srt[j]);
        dis[node]    = rsqrtf(sum);
        starts[node] = base + s;
        ends[node]   = base + t;
    }
}

// ---- z[r][h] = bf16( dis[r] * dot(x[r], W[h]) ) via MFMA bf16 ----
__global__ __launch_bounds__(256) void k_transform_mfma(
    const float* __restrict__ x, const unsigned short* __restrict__ Wbf,
    const float* __restrict__ dis, unsigned short* __restrict__ z, int N)
{
    const int wid  = (blockIdx.x * blockDim.x + threadIdx.x) >> 6;
    const int lane = threadIdx.x & 63;
    const int r0   = wid * 16;
    if (r0 >= N) return;
    const int lr = lane & 15;
    const int kg = lane >> 4;

    const float* xrow = x + (size_t)(r0 + lr) * 256;

    f32x4_t acc[8];
#pragma unroll
    for (int n = 0; n < 8; ++n) acc[n] = (f32x4_t){0.f, 0.f, 0.f, 0.f};

    for (int k0 = 0; k0 < 256; k0 += 32) {
        const int kb = k0 + kg * 8;
        float4 a0 = *reinterpret_cast<const float4*>(xrow + kb);
        float4 a1 = *reinterpret_cast<const float4*>(xrow + kb + 4);
        short8_t af;
        af[0] = (short)f2bf(a0.x); af[1] = (short)f2bf(a0.y);
        af[2] = (short)f2bf(a0.z); af[3] = (short)f2bf(a0.w);
        af[4] = (short)f2bf(a1.x); af[5] = (short)f2bf(a1.y);
        af[6] = (short)f2bf(a1.z); af[7] = (short)f2bf(a1.w);
#pragma unroll
        for (int n = 0; n < 8; ++n) {
            short8_t bf = *reinterpret_cast<const short8_t*>(
                Wbf + (size_t)(n * 16 + lr) * 256 + kb);
            acc[n] = __builtin_amdgcn_mfma_f32_16x16x32_bf16(af, bf, acc[n], 0, 0, 0);
        }
    }

    float dsc[4];
#pragma unroll
    for (int r = 0; r < 4; ++r) dsc[r] = dis[r0 + kg * 4 + r];

    // D layout: col = lane&15, row = (lane>>4)*4 + reg   [m89/m91]
#pragma unroll
    for (int n = 0; n < 8; ++n) {
#pragma unroll
        for (int r = 0; r < 4; ++r) {
            const int orow = r0 + kg * 4 + r;
            z[(size_t)orow * 128 + n * 16 + lr] = f2bf(dsc[r] * acc[n][r]);
        }
    }
}

// ---- hop: one wave per dst node, unroll-8 independent gathers ----
// acc = z[c] + sum w*z[r];  FINAL: out=dis*acc+bias (f32); else bf16(dis^2*acc)
template <bool FINAL>
__global__ __launch_bounds__(256) void k_hop(
    const int* __restrict__ starts, const int* __restrict__ ends,
    const unsigned int* __restrict__ meta,
    const float* __restrict__ dis, const unsigned int* __restrict__ hin,
    const float* __restrict__ bias, void* __restrict__ hout, int N)
{
    const int wave = threadIdx.x >> 6;
    const int lane = threadIdx.x & 63;
    const int node = blockIdx.x * 4 + wave;
    if (node >= N) return;

    const int s = __builtin_amdgcn_readfirstlane(starts[node]);
    const int t = __builtin_amdgcn_readfirstlane(ends[node]);
    const float d = dis[node];

    unsigned int v = hin[(size_t)node * 64 + lane];
    float ax = bf_lo(v), ay = bf_hi(v);            // self term z[c]

    int j = s;
    for (; j + 8 <= t; j += 8) {
        unsigned int m0 = meta[j],     m1 = meta[j + 1];
        unsigned int m2 = meta[j + 2], m3 = meta[j + 3];
        unsigned int m4 = meta[j + 4], m5 = meta[j + 5];
        unsigned int m6 = meta[j + 6], m7 = meta[j + 7];
        unsigned int u0 = hin[(size_t)(m0 & 0xffffu) * 64 + lane];
        unsigned int u1 = hin[(size_t)(m1 & 0xffffu) * 64 + lane];
        unsigned int u2 = hin[(size_t)(m2 & 0xffffu) * 64 + lane];
        unsigned int u3 = hin[(size_t)(m3 & 0xffffu) * 64 + lane];
        unsigned int u4 = hin[(size_t)(m4 & 0xffffu) * 64 + lane];
        unsigned int u5 = hin[(size_t)(m5 & 0xffffu) * 64 + lane];
        unsigned int u6 = hin[(size_t)(m6 & 0xffffu) * 64 + lane];
        unsigned int u7 = hin[(size_t)(m7 & 0xffffu) * 64 + lane];
        ax += bf_hi(m0) * bf_lo(u0); ay += bf_hi(m0) * bf_hi(u0);
        ax += bf_hi(m1) * bf_lo(u1); ay += bf_hi(m1) * bf_hi(u1);
        ax += bf_hi(m2) * bf_lo(u2); ay += bf_hi(m2) * bf_hi(u2);
        ax += bf_hi(m3) * bf_lo(u3); ay += bf_hi(m3) * bf_hi(u3);
        ax += bf_hi(m4) * bf_lo(u4); ay += bf_hi(m4) * bf_hi(u4);
        ax += bf_hi(m5) * bf_lo(u5); ay += bf_hi(m5) * bf_hi(u5);
        ax += bf_hi(m6) * bf_lo(u6); ay += bf_hi(m6) * bf_hi(u6);
        ax += bf_hi(m7) * bf_lo(u7); ay += bf_hi(m7) * bf_hi(u7);
    }
    for (; j < t; ++j) {
        unsigned int m = meta[j];
        const float w = bf_hi(m);
        unsigned int u = hin[(size_t)(m & 0xffffu) * 64 + lane];
        ax += w * bf_lo(u); ay += w * bf_hi(u);
    }

    if (FINAL) {
        float2 bv = reinterpret_cast<const float2*>(bias)[lane];
        float2 o; o.x = d * ax + bv.x; o.y = d * ay + bv.y;
        reinterpret_cast<float2*>(hout)[(size_t)node * 64 + lane] = o;
    } else {
        const float d2 = d * d;
        unsigned int p = (unsigned int)f2bf(d2 * ax) |
                         ((unsigned int)f2bf(d2 * ay) << 16);
        reinterpret_cast<unsigned int*>(hout)[(size_t)node * 64 + lane] = p;
    }
}

extern "C" void kernel_launch(void* const* d_in, const int* in_sizes, int n_in,
                              void* d_out, int out_size, void* d_ws, size_t ws_size,
                              hipStream_t stream)
{
    const float* x  = (const float*)d_in[0];
    const int*   ei = (const int*)d_in[1];     // int32 (harness converts)
    const float* ew = (const float*)d_in[2];
    const float* W  = (const float*)d_in[3];
    const float* b  = (const float*)d_in[4];

    const int E  = in_sizes[2];
    const int H  = in_sizes[4];        // 128
    const int T  = in_sizes[3] / H;    // 256
    const int N  = in_sizes[0] / T;    // 50000  (< 65536: 16-bit ids valid)
    const int WT = in_sizes[3];        // 32768
    const int NB = (N + BK - 1) / BK;  // 196 buckets

    const int* rows = ei;              // sources
    const int* cols = ei + E;          // targets (aggregation index)

    // ---- workspace ----
    char* wsb = (char*)d_ws;
    unsigned int*   z    = (unsigned int*)wsb;   wsb += (size_t)N * (H / 2) * 4;  // 12.8 MB
    unsigned int*   z1   = (unsigned int*)wsb;   wsb += (size_t)N * (H / 2) * 4;  // 12.8 MB
    unsigned int*   meta = (unsigned int*)wsb;   wsb += (size_t)NB * CAP * 4;     // 6.4 MB
    unsigned short* Wbf  = (unsigned short*)wsb; wsb += (size_t)WT * 2;           // 64 KB
    float*          dis  = (float*)wsb;          wsb += (size_t)N * 4;
    int*            sta  = (int*)wsb;            wsb += (size_t)N * 4;
    int*            end_ = (int*)wsb;            wsb += (size_t)N * 4;
    int*            tails= (int*)wsb;            wsb += (size_t)NB * 4;
    // bucket staging aliases z1 (dead until hop1 output): bwr 6.4MB + bcl 1.6MB
    unsigned int*   bwr  = z1;                                  // NB*CAP*4
    unsigned char*  bcl  = (unsigned char*)(z1 + (size_t)NB * CAP);

    float* out = (float*)d_out;

    // CSR build: bucket two-pass
    hipMemsetAsync(tails, 0, (size_t)NB * 4, stream);
    {
        const int nblkA = (E + CHUNK - 1) / CHUNK;   // 196 (covers WT too)
        k_passA<<<nblkA, 256, 0, stream>>>(rows, cols, ew, E,
                                           bwr, bcl, tails, W, Wbf, WT);
        k_passB<<<NB, 256, 0, stream>>>(bwr, bcl, tails,
                                        meta, sta, end_, dis, N);
    }

    // transform: z = bf16(dis * (X W^T))
    {
        int waves  = (N + 15) / 16;
        int blocks = (waves + 3) / 4;
        k_transform_mfma<<<blocks, 256, 0, stream>>>(
            x, Wbf, dis, (unsigned short*)z, N);
    }

    // hops (hop1 overwrites z1 -> bucket staging dead by then)
    const int gH = (N + 3) / 4;
    k_hop<false><<<gH, 256, 0, stream>>>(sta, end_, meta, dis, z, nullptr, z1, N);
    k_hop<true ><<<gH, 256, 0, stream>>>(sta, end_, meta, dis, z1, b, out, N);
}